// Round 7
// baseline (119.375 us; speedup 1.0000x reference)
//
#include <hip/hip_runtime.h>
#include <hip/hip_bf16.h>

// Problem constants
#define OUT_H 14
#define OUT_W 14
#define C_CH  256
#define SRC_H 200
#define SRC_W 304
#define M_ROI 1024
#define PLANE   (SRC_H * SRC_W)       // 60800
#define OUT_HW  (OUT_H * OUT_W)       // 196

// Block = (CPB channels, ROIS_PB rois). XCD channel-major schedule: XCD x
// owns channels [x*32, x*32+32), walks them in groups of CPB; all 128 roi-
// chunks of a group are concurrent -> cross-roi reuse stays in the XCD L2.
#define ROIS_PB 8
#define CHUNKS  (M_ROI / ROIS_PB)     // 128
#define NXCD    8
#define CH_PER_XCD (C_CH / NXCD)      // 32
#define CPB     4                     // channels per block
#define GRPS_PER_XCD (CH_PER_XCD / CPB) // 8
#define ELEMS   (ROIS_PB * OUT_HW)    // 1568
#define BLK     320                   // 5 waves; 1568/320 -> 5 iters, 2% tail
#define NITER   ((ELEMS + BLK - 1) / BLK)  // 5

typedef float f2 __attribute__((ext_vector_type(2), aligned(4)));

__global__ __launch_bounds__(BLK) void roi_crop_kernel(
    const float* __restrict__ src,
    const float* __restrict__ rois,
    float* __restrict__ out)
{
    const int bid = blockIdx.x;
    // bid % 8 = XCD (hardware round-robin). Per XCD: j = bid>>3 walks
    // channel-group-major, roi-chunk minor.
    const int x     = bid & (NXCD - 1);
    const int j     = bid >> 3;              // 0..1023 per XCD
    const int g     = j >> 7;                // channel group within XCD
    const int chunk = j & (CHUNKS - 1);      // roi chunk
    const int c0    = x * CH_PER_XCD + g * CPB;
    const int roi0  = chunk * ROIS_PB;
    const int t     = threadIdx.x;

    // Flat per-block table: one entry per (roi-local element).
    // {bits(src_off @ c0), wx, wy, bits(out_off @ c0)}
    __shared__ float4 tbl[ELEMS];            // 25088 B
    // Per-roi mini-tables (phase 1 -> phase 2 only). Clamp folded:
    //  row: base=min(y0,198)*304, wy += (y0==199)
    //  col: base=min(x0,302),     wx += (x0==303)
    __shared__ int   s_row[ROIS_PB * OUT_H];
    __shared__ float s_wy [ROIS_PB * OUT_H];
    __shared__ int   s_col[ROIS_PB * OUT_W];
    __shared__ float s_wx [ROIS_PB * OUT_W];
    __shared__ int   s_pb[ROIS_PB];          // (b*256 + c0) * PLANE
    __shared__ int   s_ob[ROIS_PB];          // rm*50176 + c0*196

    // ---- Phase 1: per-roi separable tables (224 threads) ----
    if (t < ROIS_PB * (OUT_H + OUT_W)) {
        const int r = t / (OUT_H + OUT_W);
        const int e = t - r * (OUT_H + OUT_W);
        const int rm = roi0 + r;

        float bf = rois[rm * 5 + 0];
        float x1 = rois[rm * 5 + 1];
        float y1 = rois[rm * 5 + 2];
        float x2 = rois[rm * 5 + 3];
        float y2 = rois[rm * 5 + 4];

        // KEEP_AR, _AR = 1.0
        float h  = y2 - y1 + 1.0f;
        float w  = x2 - x1 + 1.0f;
        float ew = (h - w) * 0.5f;
        float eh = (w - h) * 0.5f;
        if (ew > 0.0f) { x1 -= ew; x2 += ew; }
        else           { y1 -= eh; y2 += eh; }

        // EXTEND_RATIO = 0.1 -> each side + size*0.05
        float sw = x2 - x1 + 1.0f;
        float sh = y2 - y1 + 1.0f;
        x1 -= sw * 0.05f; x2 += sw * 0.05f;
        y1 -= sh * 0.05f; y2 += sh * 0.05f;

        if (e < OUT_H) {
            float ty = (float)e * (1.0f / (OUT_H - 1));
            float ys = y1 + (y2 - y1) * ty;
            ys = fminf(fmaxf(ys, 0.0f), (float)(SRC_H - 1));
            float y0f = floorf(ys);
            int   y0  = (int)y0f;
            s_row[r * OUT_H + e] = min(y0, SRC_H - 2) * SRC_W;
            s_wy [r * OUT_H + e] = (ys - y0f) + (y0 > SRC_H - 2 ? 1.0f : 0.0f);
            if (e == 0) {
                s_pb[r] = ((int)bf * C_CH + c0) * PLANE;
                s_ob[r] = rm * (C_CH * OUT_HW) + c0 * OUT_HW;
            }
        } else {
            int i = e - OUT_H;
            float tx = (float)i * (1.0f / (OUT_W - 1));
            float xs = x1 + (x2 - x1) * tx;
            xs = fminf(fmaxf(xs, 0.0f), (float)(SRC_W - 1));
            float x0f = floorf(xs);
            int   x0  = (int)x0f;
            s_col[r * OUT_W + i] = min(x0, SRC_W - 2);
            s_wx [r * OUT_W + i] = (xs - x0f) + (x0 > SRC_W - 2 ? 1.0f : 0.0f);
        }
    }
    __syncthreads();

    // ---- Phase 2: flat element table (decode done ONCE per CPB channels) ----
#pragma unroll
    for (int k = 0; k < NITER; ++k) {
        int idx = t + k * BLK;
        if (idx < ELEMS) {
            unsigned u  = (unsigned)idx;
            unsigned r  = u / 196u;
            unsigned p  = u - r * 196u;
            unsigned oy = p / 14u;
            unsigned ox = p - oy * 14u;
            int soff = s_pb[r] + s_row[r * OUT_H + oy] + s_col[r * OUT_W + ox];
            int ooff = s_ob[r] + (int)p;
            tbl[idx] = make_float4(__int_as_float(soff),
                                   s_wx[r * OUT_W + ox],
                                   s_wy[r * OUT_H + oy],
                                   __int_as_float(ooff));
        }
    }
    __syncthreads();

    // ---- Phase 3: CPB cheap channel passes ----
#pragma unroll 1
    for (int cc = 0; cc < CPB; ++cc) {
        const float* __restrict__ srcC = src + (size_t)cc * PLANE;
        float* __restrict__ outC = out + (size_t)cc * OUT_HW;
#pragma unroll
        for (int k = 0; k < NITER; ++k) {
            int idx = t + k * BLK;
            if (idx < ELEMS) {
                float4 e = tbl[idx];               // one ds_read_b128
                int soff = __float_as_int(e.x);
                int ooff = __float_as_int(e.w);

                const float* ptr = srcC + soff;
                f2 top = *(const f2*)ptr;            // (r0,c0),(r0,c0+1)
                f2 bot = *(const f2*)(ptr + SRC_W);  // (r1,c0),(r1,c0+1)

                float tv = top.x + (top.y - top.x) * e.y;
                float bv = bot.x + (bot.y - bot.x) * e.y;
                __builtin_nontemporal_store(tv + (bv - tv) * e.z, outC + ooff);
            }
        }
    }
}

extern "C" void kernel_launch(void* const* d_in, const int* in_sizes, int n_in,
                              void* d_out, int out_size, void* d_ws, size_t ws_size,
                              hipStream_t stream)
{
    const float* src  = (const float*)d_in[0];
    const float* rois = (const float*)d_in[1];
    float* out = (float*)d_out;

    dim3 grid(NXCD * GRPS_PER_XCD * CHUNKS);   // 8192 blocks
    dim3 block(BLK);
    roi_crop_kernel<<<grid, block, 0, stream>>>(src, rois, out);
}

// Round 8
// 108.723 us; speedup vs baseline: 1.0980x; 1.0980x over previous
//
#include <hip/hip_runtime.h>
#include <hip/hip_bf16.h>

// Problem constants
#define OUT_H 14
#define OUT_W 14
#define C_CH  256
#define SRC_H 200
#define SRC_W 304
#define M_ROI 1024
#define PLANE   (SRC_H * SRC_W)       // 60800
#define OUT_HW  (OUT_H * OUT_W)       // 196

// Block = (CPB=2 channels, 8 rois). XCD channel-major schedule: XCD x owns
// channels [x*32, x*32+32) in groups of 2; all 128 roi-chunks of a group are
// concurrent. Resident window/XCD ~1.4 groups x 2ch x 972KB = 2.7MB < 4MB L2
// -> cross-roi line reuse stays in L2 (R7's CPB=4 blew this: 5.4MB, FETCH+36%).
#define ROIS_PB 8
#define CHUNKS  (M_ROI / ROIS_PB)     // 128
#define NXCD    8
#define CH_PER_XCD (C_CH / NXCD)      // 32
#define CPB     2
#define GRPS_PER_XCD (CH_PER_XCD / CPB) // 16
#define ELEMS   (ROIS_PB * OUT_HW)    // 1568
#define BLK     320                   // 5 waves
#define NITER   ((ELEMS + BLK - 1) / BLK)  // 5

typedef float f2 __attribute__((ext_vector_type(2), aligned(4)));

__global__ __launch_bounds__(BLK) void roi_crop_kernel(
    const float* __restrict__ src,
    const float* __restrict__ rois,
    float* __restrict__ out)
{
    const int bid = blockIdx.x;
    // bid % 8 = XCD (hardware round-robin). Per XCD: channel-group major,
    // roi-chunk minor.
    const int x     = bid & (NXCD - 1);
    const int j     = bid >> 3;              // 0..2047 per XCD
    const int g     = j >> 7;                // channel group (0..15)
    const int chunk = j & (CHUNKS - 1);      // roi chunk (0..127)
    const int c0    = x * CH_PER_XCD + g * CPB;
    const int roi0  = chunk * ROIS_PB;
    const int t     = threadIdx.x;

    // Flat per-block element table: {bits(src_off@c0), wx, wy, bits(out_off@c0)}
    __shared__ float4 tbl[ELEMS];            // 25088 B
    // Per-roi mini-tables (phase 1 -> 2 only). Clamp folded:
    //  row: base=min(y0,198)*304, wy += (y0==199)
    //  col: base=min(x0,302),     wx += (x0==303)
    __shared__ int   s_row[ROIS_PB * OUT_H];
    __shared__ float s_wy [ROIS_PB * OUT_H];
    __shared__ int   s_col[ROIS_PB * OUT_W];
    __shared__ float s_wx [ROIS_PB * OUT_W];
    __shared__ int   s_pb[ROIS_PB];
    __shared__ int   s_ob[ROIS_PB];

    // ---- Phase 1: per-roi separable tables (224 threads) ----
    if (t < ROIS_PB * (OUT_H + OUT_W)) {
        const int r = t / (OUT_H + OUT_W);
        const int e = t - r * (OUT_H + OUT_W);
        const int rm = roi0 + r;

        float bf = rois[rm * 5 + 0];
        float x1 = rois[rm * 5 + 1];
        float y1 = rois[rm * 5 + 2];
        float x2 = rois[rm * 5 + 3];
        float y2 = rois[rm * 5 + 4];

        // KEEP_AR, _AR = 1.0
        float h  = y2 - y1 + 1.0f;
        float w  = x2 - x1 + 1.0f;
        float ew = (h - w) * 0.5f;
        float eh = (w - h) * 0.5f;
        if (ew > 0.0f) { x1 -= ew; x2 += ew; }
        else           { y1 -= eh; y2 += eh; }

        // EXTEND_RATIO = 0.1 -> each side + size*0.05
        float sw = x2 - x1 + 1.0f;
        float sh = y2 - y1 + 1.0f;
        x1 -= sw * 0.05f; x2 += sw * 0.05f;
        y1 -= sh * 0.05f; y2 += sh * 0.05f;

        if (e < OUT_H) {
            float ty = (float)e * (1.0f / (OUT_H - 1));
            float ys = y1 + (y2 - y1) * ty;
            ys = fminf(fmaxf(ys, 0.0f), (float)(SRC_H - 1));
            float y0f = floorf(ys);
            int   y0  = (int)y0f;
            s_row[r * OUT_H + e] = min(y0, SRC_H - 2) * SRC_W;
            s_wy [r * OUT_H + e] = (ys - y0f) + (y0 > SRC_H - 2 ? 1.0f : 0.0f);
            if (e == 0) {
                s_pb[r] = ((int)bf * C_CH + c0) * PLANE;
                s_ob[r] = rm * (C_CH * OUT_HW) + c0 * OUT_HW;
            }
        } else {
            int i = e - OUT_H;
            float tx = (float)i * (1.0f / (OUT_W - 1));
            float xs = x1 + (x2 - x1) * tx;
            xs = fminf(fmaxf(xs, 0.0f), (float)(SRC_W - 1));
            float x0f = floorf(xs);
            int   x0  = (int)x0f;
            s_col[r * OUT_W + i] = min(x0, SRC_W - 2);
            s_wx [r * OUT_W + i] = (xs - x0f) + (x0 > SRC_W - 2 ? 1.0f : 0.0f);
        }
    }
    __syncthreads();

    // ---- Phase 2: flat element table (decode ONCE per 2 channels) ----
#pragma unroll
    for (int k = 0; k < NITER; ++k) {
        int idx = t + k * BLK;
        if (idx < ELEMS) {
            unsigned u  = (unsigned)idx;
            unsigned r  = u / 196u;
            unsigned p  = u - r * 196u;
            unsigned oy = p / 14u;
            unsigned ox = p - oy * 14u;
            int soff = s_pb[r] + s_row[r * OUT_H + oy] + s_col[r * OUT_W + ox];
            int ooff = s_ob[r] + (int)p;
            tbl[idx] = make_float4(__int_as_float(soff),
                                   s_wx[r * OUT_W + ox],
                                   s_wy[r * OUT_H + oy],
                                   __int_as_float(ooff));
        }
    }
    __syncthreads();

    // ---- Phase 3: 2 cheap channel passes ----
#pragma unroll 1
    for (int cc = 0; cc < CPB; ++cc) {
        const float* __restrict__ srcC = src + (size_t)cc * PLANE;
        float* __restrict__ outC = out + (size_t)cc * OUT_HW;
#pragma unroll
        for (int k = 0; k < NITER; ++k) {
            int idx = t + k * BLK;
            if (idx < ELEMS) {
                float4 e = tbl[idx];               // one ds_read_b128
                int soff = __float_as_int(e.x);
                int ooff = __float_as_int(e.w);

                const float* ptr = srcC + soff;
                f2 top = *(const f2*)ptr;            // (r0,c0),(r0,c0+1)
                f2 bot = *(const f2*)(ptr + SRC_W);  // (r1,c0),(r1,c0+1)

                float tv = top.x + (top.y - top.x) * e.y;
                float bv = bot.x + (bot.y - bot.x) * e.y;
                __builtin_nontemporal_store(tv + (bv - tv) * e.z, outC + ooff);
            }
        }
    }
}

extern "C" void kernel_launch(void* const* d_in, const int* in_sizes, int n_in,
                              void* d_out, int out_size, void* d_ws, size_t ws_size,
                              hipStream_t stream)
{
    const float* src  = (const float*)d_in[0];
    const float* rois = (const float*)d_in[1];
    float* out = (float*)d_out;

    dim3 grid(NXCD * GRPS_PER_XCD * CHUNKS);   // 16384 blocks
    dim3 block(BLK);
    roi_crop_kernel<<<grid, block, 0, stream>>>(src, rois, out);
}

// Round 9
// 107.513 us; speedup vs baseline: 1.1103x; 1.0113x over previous
//
#include <hip/hip_runtime.h>
#include <hip/hip_bf16.h>

// Problem constants
#define OUT_H 14
#define OUT_W 14
#define C_CH  256
#define SRC_H 200
#define SRC_W 304
#define M_ROI 1024
#define PLANE   (SRC_H * SRC_W)       // 60800
#define OUT_HW  (OUT_H * OUT_W)       // 196

// Block = (CPB=2 channels, 8 rois). XCD channel-major schedule: XCD x owns
// channels [x*32, x*32+32) in groups of 2; all 128 roi-chunks of a group are
// concurrent. Resident window/XCD ~2.7MB < 4MB L2 (CPB=4 blew it: FETCH+36%).
#define ROIS_PB 8
#define CHUNKS  (M_ROI / ROIS_PB)     // 128
#define NXCD    8
#define CH_PER_XCD (C_CH / NXCD)      // 32
#define CPB     2
#define GRPS_PER_XCD (CH_PER_XCD / CPB) // 16
#define ELEMS   (ROIS_PB * OUT_HW)    // 1568
#define BLK     320                   // 5 waves
#define NITER   ((ELEMS + BLK - 1) / BLK)  // 5

typedef float f2 __attribute__((ext_vector_type(2), aligned(4)));

__global__ __launch_bounds__(BLK, 5) void roi_crop_kernel(
    const float* __restrict__ src,
    const float* __restrict__ rois,
    float* __restrict__ out)
{
    const int bid = blockIdx.x;
    // bid % 8 = XCD (hardware round-robin). Per XCD: channel-group major,
    // roi-chunk minor.
    const int x     = bid & (NXCD - 1);
    const int j     = bid >> 3;              // 0..2047 per XCD
    const int g     = j >> 7;                // channel group (0..15)
    const int chunk = j & (CHUNKS - 1);      // roi chunk (0..127)
    const int c0    = x * CH_PER_XCD + g * CPB;
    const int roi0  = chunk * ROIS_PB;
    const int t     = threadIdx.x;

    // Flat per-block element table: {bits(src_off@c0), wx, wy, bits(out_off@c0)}
    __shared__ float4 tbl[ELEMS];            // 25088 B
    // Per-roi mini-tables (phase 1 -> 2 only). Clamp folded:
    //  row: base=min(y0,198)*304, wy += (y0==199)
    //  col: base=min(x0,302),     wx += (x0==303)
    __shared__ int   s_row[ROIS_PB * OUT_H];
    __shared__ float s_wy [ROIS_PB * OUT_H];
    __shared__ int   s_col[ROIS_PB * OUT_W];
    __shared__ float s_wx [ROIS_PB * OUT_W];
    __shared__ int   s_pb[ROIS_PB];
    __shared__ int   s_ob[ROIS_PB];

    // ---- Phase 1: per-roi separable tables (224 threads) ----
    if (t < ROIS_PB * (OUT_H + OUT_W)) {
        const int r = t / (OUT_H + OUT_W);
        const int e = t - r * (OUT_H + OUT_W);
        const int rm = roi0 + r;

        float bf = rois[rm * 5 + 0];
        float x1 = rois[rm * 5 + 1];
        float y1 = rois[rm * 5 + 2];
        float x2 = rois[rm * 5 + 3];
        float y2 = rois[rm * 5 + 4];

        // KEEP_AR, _AR = 1.0
        float h  = y2 - y1 + 1.0f;
        float w  = x2 - x1 + 1.0f;
        float ew = (h - w) * 0.5f;
        float eh = (w - h) * 0.5f;
        if (ew > 0.0f) { x1 -= ew; x2 += ew; }
        else           { y1 -= eh; y2 += eh; }

        // EXTEND_RATIO = 0.1 -> each side + size*0.05
        float sw = x2 - x1 + 1.0f;
        float sh = y2 - y1 + 1.0f;
        x1 -= sw * 0.05f; x2 += sw * 0.05f;
        y1 -= sh * 0.05f; y2 += sh * 0.05f;

        if (e < OUT_H) {
            float ty = (float)e * (1.0f / (OUT_H - 1));
            float ys = y1 + (y2 - y1) * ty;
            ys = fminf(fmaxf(ys, 0.0f), (float)(SRC_H - 1));
            float y0f = floorf(ys);
            int   y0  = (int)y0f;
            s_row[r * OUT_H + e] = min(y0, SRC_H - 2) * SRC_W;
            s_wy [r * OUT_H + e] = (ys - y0f) + (y0 > SRC_H - 2 ? 1.0f : 0.0f);
            if (e == 0) {
                s_pb[r] = ((int)bf * C_CH + c0) * PLANE;
                s_ob[r] = rm * (C_CH * OUT_HW) + c0 * OUT_HW;
            }
        } else {
            int i = e - OUT_H;
            float tx = (float)i * (1.0f / (OUT_W - 1));
            float xs = x1 + (x2 - x1) * tx;
            xs = fminf(fmaxf(xs, 0.0f), (float)(SRC_W - 1));
            float x0f = floorf(xs);
            int   x0  = (int)x0f;
            s_col[r * OUT_W + i] = min(x0, SRC_W - 2);
            s_wx [r * OUT_W + i] = (xs - x0f) + (x0 > SRC_W - 2 ? 1.0f : 0.0f);
        }
    }
    __syncthreads();

    // ---- Phase 2: flat element table (decode ONCE per 2 channels) ----
#pragma unroll
    for (int k = 0; k < NITER; ++k) {
        int idx = t + k * BLK;
        if (idx < ELEMS) {
            unsigned u  = (unsigned)idx;
            unsigned r  = u / 196u;
            unsigned p  = u - r * 196u;
            unsigned oy = p / 14u;
            unsigned ox = p - oy * 14u;
            int soff = s_pb[r] + s_row[r * OUT_H + oy] + s_col[r * OUT_W + ox];
            int ooff = s_ob[r] + (int)p;
            tbl[idx] = make_float4(__int_as_float(soff),
                                   s_wx[r * OUT_W + ox],
                                   s_wy[r * OUT_H + oy],
                                   __int_as_float(ooff));
        }
    }
    __syncthreads();

    // ---- Phase 3: fused 2-channel pass. 4 independent gathers in flight
    // per iteration (2x the MLP of the split version); tbl read once. ----
#pragma unroll
    for (int k = 0; k < NITER; ++k) {
        int idx = t + k * BLK;
        if (idx < ELEMS) {
            float4 e = tbl[idx];               // one ds_read_b128
            int soff = __float_as_int(e.x);
            int ooff = __float_as_int(e.w);

            const float* p0 = src + soff;            // channel c0
            const float* p1 = p0 + PLANE;            // channel c0+1
            f2 t0 = *(const f2*)p0;
            f2 b0 = *(const f2*)(p0 + SRC_W);
            f2 t1 = *(const f2*)p1;
            f2 b1 = *(const f2*)(p1 + SRC_W);

            float tv0 = t0.x + (t0.y - t0.x) * e.y;
            float bv0 = b0.x + (b0.y - b0.x) * e.y;
            __builtin_nontemporal_store(tv0 + (bv0 - tv0) * e.z, out + ooff);

            float tv1 = t1.x + (t1.y - t1.x) * e.y;
            float bv1 = b1.x + (b1.y - b1.x) * e.y;
            __builtin_nontemporal_store(tv1 + (bv1 - tv1) * e.z,
                                        out + ooff + OUT_HW);
        }
    }
}

extern "C" void kernel_launch(void* const* d_in, const int* in_sizes, int n_in,
                              void* d_out, int out_size, void* d_ws, size_t ws_size,
                              hipStream_t stream)
{
    const float* src  = (const float*)d_in[0];
    const float* rois = (const float*)d_in[1];
    float* out = (float*)d_out;

    dim3 grid(NXCD * GRPS_PER_XCD * CHUNKS);   // 16384 blocks
    dim3 block(BLK);
    roi_crop_kernel<<<grid, block, 0, stream>>>(src, rois, out);
}